// Round 7
// baseline (722.346 us; speedup 1.0000x reference)
//
#include <hip/hip_runtime.h>
#include <hip/hip_bf16.h>

// 2-layer GCN + CORAL head. MFMA GEMM + XCD-sliced bf16 aggregation.
//  - edge compaction: int64 edge_index -> int32 src/dst + fused degree count
//  - counting sort: dst-partitioned fill over compact arrays (XCD-local writes)
//  - split-bf16 (hi/lo) MFMA GEMM; epilogue scales row by deg_inv_sqrt and
//    stores bf16 in SLICE-MAJOR planes: 8 slices x 16 cols (3.2 MB/slice)
//  - aggregation: slice s handled only by blocks blockIdx%8==s -> slice plane
//    stays resident in that XCD's private L2; gathers are L2 hits.
//    wave = 1 node, 8 edges x 8 lanes (u32 = 2 bf16 cols/lane), xor-reduce
//  - layer-1 agg fuses relu + bf16 hi/lo (slice planes, feeds layer-2 GEMM)
//  - layer-2 agg emits per-slice head partials; reduce_head adds th_bias

#define FEAT 128
#define CHUNK 4096
typedef unsigned short u16;
typedef unsigned int u32;
typedef __attribute__((ext_vector_type(8))) short bf16x8;
typedef __attribute__((ext_vector_type(4))) float f32x4;
#define MFMA16 __builtin_amdgcn_mfma_f32_16x16x32_bf16

__device__ inline u16 f2bf(float f) {
    __hip_bfloat16 b = __float2bfloat16(f);
    return __builtin_bit_cast(u16, b);
}
__device__ inline float bf2f(u16 u) {
    __hip_bfloat16 b = __builtin_bit_cast(__hip_bfloat16, u);
    return __bfloat162float(b);
}
__device__ inline float blo(u32 m) { return __uint_as_float(m << 16); }
__device__ inline float bhi(u32 m) { return __uint_as_float(m & 0xffff0000u); }

// ------------- compact edges to int32 + degree histogram (detect inlined) ----
__global__ __launch_bounds__(256) void compact_count(const int* __restrict__ p,
                                                     int* __restrict__ src32,
                                                     int* __restrict__ dst32,
                                                     int* __restrict__ cnt, int E) {
    __shared__ int sflag;
    if (threadIdx.x < 64) {
        int v = p[2 * (int)threadIdx.x + 1];
        unsigned long long b = __ballot(v != 0);
        if (threadIdx.x == 0) sflag = (b == 0ull) ? 1 : 0;
    }
    __syncthreads();
    const int m = sflag;
    int i = blockIdx.x * 256 + threadIdx.x;
    if (i >= E) return;
    int s, d;
    if (m) { s = p[2 * (size_t)i]; d = p[2 * ((size_t)E + i)]; }
    else   { s = p[(size_t)i];     d = p[(size_t)E + i]; }
    src32[i] = s;
    dst32[i] = d;
    atomicAdd(&cnt[d], 1);
}

// ---------------- scan1: block-exclusive scan + fused deg_inv_sqrt ----------
__global__ void scan1(const int* __restrict__ cnt, int* __restrict__ out,
                      int* __restrict__ bsum, float* __restrict__ dis, int n) {
    __shared__ int tmp[256];
    int base = blockIdx.x * 2048;
    int idx = base + threadIdx.x * 8;
    int v[8]; int s = 0;
#pragma unroll
    for (int i = 0; i < 8; ++i) {
        int id = idx + i;
        v[i] = (id < n) ? cnt[id] : 0;
        s += v[i];
        if (id < n) dis[id] = 1.0f / sqrtf((float)v[i] + 1.0f);
    }
    tmp[threadIdx.x] = s;
    __syncthreads();
    for (int off = 1; off < 256; off <<= 1) {
        int t = (threadIdx.x >= (unsigned)off) ? tmp[threadIdx.x - off] : 0;
        __syncthreads();
        tmp[threadIdx.x] += t;
        __syncthreads();
    }
    int excl = (threadIdx.x == 0) ? 0 : tmp[threadIdx.x - 1];
    if (threadIdx.x == 255) bsum[blockIdx.x] = tmp[255];
    int run = excl;
#pragma unroll
    for (int i = 0; i < 8; ++i) { int id = idx + i; if (id < n) out[id] = run; run += v[i]; }
}

__global__ void scan2(int* __restrict__ bsum, int nb) {
    __shared__ int tmp[256];
    int v = (threadIdx.x < (unsigned)nb) ? bsum[threadIdx.x] : 0;
    tmp[threadIdx.x] = v;
    __syncthreads();
    for (int off = 1; off < 256; off <<= 1) {
        int t = (threadIdx.x >= (unsigned)off) ? tmp[threadIdx.x - off] : 0;
        __syncthreads();
        tmp[threadIdx.x] += t;
        __syncthreads();
    }
    int excl = (threadIdx.x == 0) ? 0 : tmp[threadIdx.x - 1];
    if (threadIdx.x < (unsigned)nb) bsum[threadIdx.x] = excl;
}

// ---------------- counting-sort fill, dst-partitioned (8 XCD slices) ---------
// pos = bsum[d>>11] + fetch_add(rowp[d]). After this kernel:
//   rowp[d] = local_excl[d] + cnt[d]  =>  beg(d) = bsum[d>>11] + rowp[d] - cnt[d]
__global__ __launch_bounds__(256) void fill_sorted(const int* __restrict__ src32,
                                                   const int* __restrict__ dst32,
                                                   int* __restrict__ rowp,
                                                   const int* __restrict__ bsum,
                                                   int* __restrict__ ssrc, int E,
                                                   int nper) {
    const int part = blockIdx.x & 7;
    const int lo = part * nper, hi = lo + nper;
    const int i0 = (int)(blockIdx.x >> 3) * CHUNK;
    const int iend = min(i0 + CHUNK, E);
    for (int i = i0 + threadIdx.x; i < iend; i += 256) {
        int d = dst32[i];
        if (d >= lo && d < hi) {
            int pos = bsum[d >> 11] + atomicAdd(&rowp[d], 1);
            ssrc[pos] = src32[i];
        }
    }
}

// W [k][col] fp32 -> transposed bf16 hi/lo Wt[col][k]
__global__ void conv_w(const float* __restrict__ W, u16* __restrict__ th,
                       u16* __restrict__ tl) {
    int idx = blockIdx.x * 256 + threadIdx.x;   // 16384
    int k = idx >> 7, col = idx & 127;
    float v = W[idx];
    u16 h = f2bf(v);
    u16 l = f2bf(v - bf2f(h));
    th[col * 128 + k] = h;
    tl[col * 128 + k] = l;
}

// ---------------- MFMA GEMM -> slice-major bf16 planes ----------------------
// G[s][r][c16]: slice s = col/16, c16 = col%16. FP32IN: X fp32, split in-reg;
// else X from h1 slice planes (hi/lo). W transposed bf16 hi/lo [col][128].
template <bool FP32IN>
__global__ __launch_bounds__(256) void gemm_mfma(
    const float* __restrict__ Xf,
    const u16* __restrict__ Xhi, const u16* __restrict__ Xlo,
    const u16* __restrict__ Whi, const u16* __restrict__ Wlo,
    const float* __restrict__ dis, u16* __restrict__ G, int n, int nt) {
    const int wave = threadIdx.x >> 6, lane = threadIdx.x & 63;
    const int l15 = lane & 15, hi4 = lane >> 4;

    bf16x8 bh[2][4], bl[2][4];
#pragma unroll
    for (int ct = 0; ct < 2; ++ct) {
        const int col = wave * 32 + ct * 16 + l15;
#pragma unroll
        for (int j = 0; j < 4; ++j) {
            const int off = col * 128 + j * 32 + hi4 * 8;
            bh[ct][j] = *(const bf16x8*)(Whi + off);
            bl[ct][j] = *(const bf16x8*)(Wlo + off);
        }
    }

    for (int rt = blockIdx.x; rt < nt; rt += gridDim.x) {
        const int r0 = rt * 16;
        const int row = min(r0 + l15, n - 1);
        bf16x8 ah[4], al[4];
        if (FP32IN) {
            const float* Xr = Xf + (size_t)row * FEAT;
#pragma unroll
            for (int j = 0; j < 4; ++j) {
                float4 v0 = *(const float4*)(Xr + j * 32 + hi4 * 8);
                float4 v1 = *(const float4*)(Xr + j * 32 + hi4 * 8 + 4);
                float vv[8] = {v0.x, v0.y, v0.z, v0.w, v1.x, v1.y, v1.z, v1.w};
                bf16x8 h8, l8;
#pragma unroll
                for (int e = 0; e < 8; ++e) {
                    u16 h = f2bf(vv[e]);
                    u16 l = f2bf(vv[e] - bf2f(h));
                    h8[e] = (short)h; l8[e] = (short)l;
                }
                ah[j] = h8; al[j] = l8;
            }
        } else {
            // A-frag cols j*32+hi4*8 .. +7 live in slice (c8>>4), offset c8&15
#pragma unroll
            for (int j = 0; j < 4; ++j) {
                const int c8 = j * 32 + hi4 * 8;
                const size_t off = (size_t)(c8 >> 4) * n * 16 +
                                   (size_t)row * 16 + (c8 & 15);
                ah[j] = *(const bf16x8*)(Xhi + off);
                al[j] = *(const bf16x8*)(Xlo + off);
            }
        }
        float dr[4];
#pragma unroll
        for (int q = 0; q < 4; ++q) {
            const int r = r0 + hi4 * 4 + q;
            dr[q] = (r < n) ? dis[r] : 0.f;
        }
#pragma unroll
        for (int ct = 0; ct < 2; ++ct) {
            f32x4 a = {0.f, 0.f, 0.f, 0.f};
#pragma unroll
            for (int j = 0; j < 4; ++j) {
                a = MFMA16(ah[j], bh[ct][j], a, 0, 0, 0);
                a = MFMA16(al[j], bh[ct][j], a, 0, 0, 0);
                a = MFMA16(ah[j], bl[ct][j], a, 0, 0, 0);
                a = MFMA16(al[j], bl[ct][j], a, 0, 0, 0);
            }
            const int s = wave * 2 + ct;   // slice
#pragma unroll
            for (int q = 0; q < 4; ++q) {
                const int r = r0 + hi4 * 4 + q;
                if (r < n)
                    G[(size_t)s * n * 16 + (size_t)r * 16 + l15] = f2bf(a[q] * dr[q]);
            }
        }
    }
}

// ---------------- XCD-sliced pull aggregate ----------------
// slice = blockIdx%8 (round-robin dispatch -> one XCD per slice; its 3.2 MB
// plane stays L2-resident). Wave = 1 node; lanes = 8 edges x 8 cols-pairs.
// MODE 0: relu(dn*sum+b) -> bf16 hi/lo slice planes
// MODE 1: per-slice CORAL partial -> part[slice][node]
template <int MODE>
__global__ __launch_bounds__(256) void agg_sliced(
    const u16* __restrict__ G, const int* __restrict__ rowp,
    const int* __restrict__ cnt, const int* __restrict__ bsum,
    const int* __restrict__ ssrc, const float* __restrict__ dis,
    const float* __restrict__ bias,
    u16* __restrict__ Ohi, u16* __restrict__ Olo,
    float* __restrict__ part, const float* __restrict__ wfc, int n) {
    const int slice = blockIdx.x & 7;
    const int wave = threadIdx.x >> 6, lane = threadIdx.x & 63;
    const int c = lane & 7, e = lane >> 3;
    const u32* __restrict__ Gs = (const u32*)G + (size_t)slice * n * 8;
    const int nstride = (int)(gridDim.x >> 3) * 4;
    for (int node = (int)(blockIdx.x >> 3) * 4 + wave; node < n; node += nstride) {
        const int cno = cnt[node];
        const int beg = bsum[node >> 11] + rowp[node] - cno;
        const int end = beg + cno;
        float ax = 0.f, ay = 0.f;
        if (e == 0) {                       // self term, counted once
            u32 m = Gs[(size_t)node * 8 + c];
            ax = blo(m); ay = bhi(m);
        }
        for (int j = beg; j < end; j += 8) {
            const int idx = j + e;
            if (idx < end) {
                const int s = ssrc[idx];
                u32 m = Gs[(size_t)s * 8 + c];
                ax += blo(m); ay += bhi(m);
            }
        }
#pragma unroll
        for (int off = 8; off < 64; off <<= 1) {
            ax += __shfl_xor(ax, off, 64);
            ay += __shfl_xor(ay, off, 64);
        }
        const float dn = dis[node];
        const float2 bv = ((const float2*)bias)[slice * 8 + c];
        const float o0 = fmaxf(fmaf(dn, ax, bv.x), 0.f);
        const float o1 = fmaxf(fmaf(dn, ay, bv.y), 0.f);
        if (MODE == 0) {
            if (e == 0) {
                u16 h0 = f2bf(o0), h1 = f2bf(o1);
                u32 hp = (u32)h0 | ((u32)h1 << 16);
                u32 lp = (u32)f2bf(o0 - bf2f(h0)) | ((u32)f2bf(o1 - bf2f(h1)) << 16);
                ((u32*)Ohi)[(size_t)slice * n * 8 + (size_t)node * 8 + c] = hp;
                ((u32*)Olo)[(size_t)slice * n * 8 + (size_t)node * 8 + c] = lp;
            }
        } else {
            const float2 wv = ((const float2*)wfc)[slice * 8 + c];
            float p = fmaf(o0, wv.x, o1 * wv.y);
#pragma unroll
            for (int off = 1; off < 8; off <<= 1) p += __shfl_xor(p, off, 64);
            if (lane == 0) part[(size_t)slice * n + node] = p;
        }
    }
}

// ---------------- head reduce: out[i][k] = thb[k] + sum_s part[s][i] --------
__global__ void reduce_head(const float* __restrict__ part,
                            const float* __restrict__ thb,
                            float* __restrict__ out, int n) {
    int i = blockIdx.x * 256 + threadIdx.x;
    if (i >= n) return;
    float t = 0.f;
#pragma unroll
    for (int s = 0; s < 8; ++s) t += part[(size_t)s * n + i];
    float4 o = {t + thb[0], t + thb[1], t + thb[2], t + thb[3]};
    ((float4*)out)[i] = o;
}

extern "C" void kernel_launch(void* const* d_in, const int* in_sizes, int n_in,
                              void* d_out, int out_size, void* d_ws, size_t ws_size,
                              hipStream_t stream) {
    const float* x   = (const float*)d_in[0];
    const int*   ei  = (const int*)d_in[1];
    const float* W1  = (const float*)d_in[2];
    const float* b1  = (const float*)d_in[3];
    const float* W2  = (const float*)d_in[4];
    const float* b2  = (const float*)d_in[5];
    const float* wfc = (const float*)d_in[6];
    const float* thb = (const float*)d_in[7];
    const int N = in_sizes[0] / FEAT;
    const int E = in_sizes[1] / 2;
    float* out = (float*)d_out;

    char* w = (char*)d_ws;
    int*   bsum  = (int*)w;                       // [<=256]
    int*   deg   = (int*)(w + 1024);              // [N]  (= cnt)
    int*   rowp  = deg + N;                       // [N]
    float* dis   = (float*)(rowp + N);            // [N]
    int*   src32 = (int*)(dis + N);               // [E]
    int*   dst32 = src32 + E;                     // [E]
    int*   ssrc  = dst32 + E;                     // [E]
    size_t off   = (((char*)(ssrc + E)) - w + 511) & ~(size_t)511;
    u16*   w1h   = (u16*)(w + off);               // [128*128]
    u16*   w1l   = w1h + 16384;
    u16*   w2h   = w1l + 16384;
    u16*   w2l   = w2h + 16384;
    u16*   g     = w2l + 16384;                   // [N*128] slice planes
    u16*   h1h   = g + (size_t)N * FEAT;          // [N*128] slice planes
    u16*   h1l   = h1h + (size_t)N * FEAT;        // [N*128] slice planes
    float* part  = (float*)(h1l + (size_t)N * FEAT);  // [8*N]

    const int nper = (N + 7) / 8;                 // dst-partition width
    const int nch  = (E + CHUNK - 1) / CHUNK;     // edge chunks per partition
    const int NB   = (N + 2047) / 2048;

    hipMemsetAsync(deg, 0, (size_t)N * 4, stream);
    compact_count<<<(E + 255) / 256, 256, 0, stream>>>(ei, src32, dst32, deg, E);
    scan1<<<NB, 256, 0, stream>>>(deg, rowp, bsum, dis, N);
    scan2<<<1, 256, 0, stream>>>(bsum, NB);
    fill_sorted<<<nch * 8, 256, 0, stream>>>(src32, dst32, rowp, bsum, ssrc, E, nper);

    conv_w<<<64, 256, 0, stream>>>(W1, w1h, w1l);
    conv_w<<<64, 256, 0, stream>>>(W2, w2h, w2l);

    const int nt = (N + 15) / 16;
    const int gblocks = nt < 1024 ? nt : 1024;
    gemm_mfma<true><<<gblocks, 256, 0, stream>>>(x, nullptr, nullptr, w1h, w1l,
                                                 dis, g, N, nt);
    agg_sliced<0><<<16384, 256, 0, stream>>>(g, rowp, deg, bsum, ssrc, dis, b1,
                                             h1h, h1l, nullptr, nullptr, N);
    gemm_mfma<false><<<gblocks, 256, 0, stream>>>(nullptr, h1h, h1l, w2h, w2l,
                                                  dis, g, N, nt);
    agg_sliced<1><<<16384, 256, 0, stream>>>(g, rowp, deg, bsum, ssrc, dis, b2,
                                             nullptr, nullptr, part, wfc, N);
    reduce_head<<<(N + 255) / 256, 256, 0, stream>>>(part, thb, out, N);
}